// Round 1
// 588.148 us; speedup vs baseline: 1.0163x; 1.0163x over previous
//
#include <hip/hip_runtime.h>

#define EPS_C 0.01f
#define NU    128
#define DIN   64
#define COUT  10

typedef float    f32x4 __attribute__((ext_vector_type(4)));
typedef _Float16 f16x4 __attribute__((ext_vector_type(4)));
typedef _Float16 f16x8 __attribute__((ext_vector_type(8)));

#define MFMA32(A, B, C) __builtin_amdgcn_mfma_f32_16x16x32_f16((A), (B), (C), 0, 0, 0)
// LDS-only barrier: vmcnt stays in flight across the per-step sync.
#define BAR() asm volatile("s_waitcnt lgkmcnt(0)\n\ts_barrier" ::: "memory")

// Transposed recurrence h^T(t+1) = h^T + eps*(A^T h^T + tanh(W^T h^T + z^T)).
// 4 waves (256 thr), wave w owns units [32w, 32w+32) = m-tiles 2w, 2w+1.
// Rationale vs 8-wave version: per-SIMD MFMA work is identical (20/step), but
// 1 wave/SIMD kills the phase-lockstep contention, per-CU redundant h ds_reads
// halve (each wave reads the SAME 4 B-frags regardless of unit count), barrier
// has 4 participants, and the wave has 4 independent depth-4 chains of ILP.
// mfma_f32_16x16x32_f16 layouts (HW-verified in prior rounds):
//   A-op: A[m = lane&15][k = quad*8 + j]
//   B-op: B[k = quad*8 + j][n = lane&15]
//   D   : D[row = quad*4 + reg][col = lane&15]
// h exchange: unit u = 32w + 16mt + 4q + r, batch lid ->
//   hbuf[np][kt=w][(2mt + (q>>1))*16 + lid][4(q&1) + r]   (f16x4 write, 2-way
//   bank aliasing only = free; reads are linear ds_read_b128, conflict-free)
__global__ __launch_bounds__(256, 1)
void rnn_core(const float* __restrict__ x,
              const float* __restrict__ E_w, const float* __restrict__ E_b,
              const float* __restrict__ B_p, const float* __restrict__ C_p,
              const float* __restrict__ D_w, const float* __restrict__ D_b,
              float* __restrict__ out, int T)
{
    const int tid  = threadIdx.x;
    const int lane = tid & 63;
    const int w    = tid >> 6;     // wave 0..3
    const int lid  = lane & 15;
    const int q    = lane >> 4;
    const int g    = blockIdx.x;   // batch group (16 rows)

    // xs[buf]: 8 steps of x in B-frag layout: [t8][kt2][lane64][8 halves]
    __shared__ __attribute__((aligned(16))) _Float16 xs[2][8 * 1024];   // 2 x 16 KB
    __shared__ __attribute__((aligned(16))) _Float16 hbuf[2][4][64][8]; // 8 KB
    __shared__ float hfin[16][NU + 4];

    // ---- one-time weight fragments (wave w: m = 32w + 16mt + lid) ----
    f16x8 AT[2][4], WT[2][4], EF[2][2];
    f32x4 ebv[2];
    #pragma unroll
    for (int mt = 0; mt < 2; ++mt) {
        const int m = w * 32 + mt * 16 + lid;
        #pragma unroll
        for (int kt = 0; kt < 4; ++kt) {
            f16x8 fa, fw;
            #pragma unroll
            for (int j = 0; j < 8; ++j) {
                const int k  = kt * 32 + q * 8 + j;
                const float dg = (k == m) ? 0.01f : 0.0f;
                fa[j] = (_Float16)(B_p[k * NU + m] - 0.6f * B_p[m * NU + k] - dg);
                fw[j] = (_Float16)(C_p[k * NU + m] - 0.6f * C_p[m * NU + k] - dg);
            }
            AT[mt][kt] = fa;  WT[mt][kt] = fw;
        }
        #pragma unroll
        for (int kt = 0; kt < 2; ++kt) {
            f16x8 fe;
            #pragma unroll
            for (int j = 0; j < 8; ++j)
                fe[j] = (_Float16)E_w[m * DIN + kt * 32 + q * 8 + j];
            EF[mt][kt] = fe;
        }
        #pragma unroll
        for (int r = 0; r < 4; ++r)
            ebv[mt][r] = E_b[w * 32 + mt * 16 + q * 4 + r];
    }

    // ---- x staging mapping (256 loader threads, 1 float4/step each) ----
    const int bb = tid & 15;        // batch row
    const int s2 = tid >> 4;        // d-quad 0..15 (d = 4*s2..4*s2+3)
    const float* xrow = x + ((size_t)(g * 16 + bb) * T) * DIN + s2 * 4;
    const int wb2 = (((s2 >> 3) * 64) + (((s2 >> 1) & 3) * 16) + bb) * 16 + (s2 & 1) * 8;

    float4 xg[8];   // one chunk = 8 steps

#define STAGE_WRITE(BUF)                                                      \
    {                                                                         \
        char* base_ = (char*)&xs[(BUF)][0];                                   \
        _Pragma("unroll")                                                     \
        for (int i2 = 0; i2 < 8; ++i2) {                                      \
            float4 v_ = xg[i2];                                               \
            f16x4 h4_;                                                        \
            h4_[0] = (_Float16)v_.x; h4_[1] = (_Float16)v_.y;                 \
            h4_[2] = (_Float16)v_.z; h4_[3] = (_Float16)v_.w;                 \
            *(f16x4*)(base_ + i2 * 2048 + wb2) = h4_;                         \
        }                                                                     \
    }

    // ---- init: zero parity-0 h buffer (4 KB = 256 x 16B); stage chunk 0 ----
    ((float4*)&hbuf[0][0][0][0])[tid] = (float4){0.f, 0.f, 0.f, 0.f};
    #pragma unroll
    for (int i = 0; i < 8; ++i)
        xg[i] = *(const float4*)(xrow + (size_t)i * DIN);
    STAGE_WRITE(0)
    __syncthreads();

    // precomputed LDS byte bases
    char* xsb = (char*)&xs[0][0] + lane * 16;                 // +buf*16384 +it*2048 +kt2*1024
    char* hrb = (char*)&hbuf[0][0][0][0] + lane * 16;         // +p*4096 +kt*1024
    char* hwb = (char*)&hbuf[0][0][0][0]
              + (w * 64 + (q >> 1) * 16 + lid) * 16 + (q & 1) * 8;  // +np*4096 +mt*512

    // ---- state init: h = 0, z_cur = z(0) ----
    f32x4 hf[2] = {{0.f,0.f,0.f,0.f}, {0.f,0.f,0.f,0.f}};
    f32x4 zc0, zc1;
    {
        f16x8 x0 = *(const f16x8*)(xsb);
        f16x8 x1 = *(const f16x8*)(xsb + 1024);
        zc0 = ebv[0];
        zc0 = MFMA32(EF[0][0], x0, zc0);
        zc0 = MFMA32(EF[0][1], x1, zc0);
        zc1 = ebv[1];
        zc1 = MFMA32(EF[1][0], x0, zc1);
        zc1 = MFMA32(EF[1][1], x1, zc1);
    }

    const int nch = T >> 3;   // 128 chunks of 8 steps
    for (int c = 0; c < nch; ++c) {
        if (c + 1 < nch) {
            const float* xr2 = xrow + (size_t)(c + 1) * 8 * DIN;
            #pragma unroll
            for (int i = 0; i < 8; ++i)
                xg[i] = *(const float4*)(xr2 + (size_t)i * DIN);
        }
        #pragma unroll
        for (int i = 0; i < 8; ++i) {
            const int t  = c * 8 + i;
            const int p  = i & 1;
            const int np = p ^ 1;

            // h B-frags (same 4 frags serve both m-tiles)
            f16x8 hB[4];
            #pragma unroll
            for (int kt = 0; kt < 4; ++kt)
                hB[kt] = *(const f16x8*)(hrb + p * 4096 + kt * 1024);

            // x B-frags for t+1 (z_next, off critical path)
            int tt = t + 1; if (tt >= T) tt = T - 1;
            char* xb = xsb + ((tt >> 3) & 1) * 16384 + (tt & 7) * 2048;
            f16x8 xfA = *(const f16x8*)(xb);
            f16x8 xfB = *(const f16x8*)(xb + 1024);

            // W chains FIRST (tanh critical path): 2 interleaved depth-4 chains
            f32x4 wa0 = zc0, wa1 = zc1;
            #pragma unroll
            for (int kt = 0; kt < 4; ++kt) {
                wa0 = MFMA32(WT[0][kt], hB[kt], wa0);
                wa1 = MFMA32(WT[1][kt], hB[kt], wa1);
            }
            // A chains + z(t+1): independent of tanh -> issue fills the VALU window
            f32x4 ya0 = {0.f,0.f,0.f,0.f}, ya1 = {0.f,0.f,0.f,0.f};
            #pragma unroll
            for (int kt = 0; kt < 4; ++kt) {
                ya0 = MFMA32(AT[0][kt], hB[kt], ya0);
                ya1 = MFMA32(AT[1][kt], hB[kt], ya1);
            }
            f32x4 zn0 = ebv[0], zn1 = ebv[1];
            zn0 = MFMA32(EF[0][0], xfA, zn0);
            zn1 = MFMA32(EF[1][0], xfA, zn1);
            zn0 = MFMA32(EF[0][1], xfB, zn0);
            zn1 = MFMA32(EF[1][1], xfB, zn1);

            // ---- epilogue: h += eps*(ya + tanh(wa)); D->B shuffled write ----
            #pragma unroll
            for (int mt = 0; mt < 2; ++mt) {
                f32x4 wa = mt ? wa1 : wa0;
                f32x4 ya = mt ? ya1 : ya0;
                f16x4 nh;
                #pragma unroll
                for (int r = 0; r < 4; ++r) {
                    // tanh(x) = 1 - 2/(exp2(x*2log2e)+1): 1 mul + 1 trans + add/rcp/fma
                    const float e2 = __builtin_amdgcn_exp2f(wa[r] * 2.8853900817779268f);
                    const float th = 1.0f - 2.0f * __builtin_amdgcn_rcpf(e2 + 1.0f);
                    const float hv = hf[mt][r] + EPS_C * (ya[r] + th);
                    hf[mt][r] = hv;
                    nh[r] = (_Float16)hv;
                }
                *(f16x4*)(hwb + np * 4096 + mt * 512) = nh;
            }
            zc0 = zn0; zc1 = zn1;

            if (i == 5 && c + 1 < nch) STAGE_WRITE((c + 1) & 1)
            BAR();   // lgkmcnt(0) + s_barrier; vmcnt stays in flight
        }
    }

    // ---- final: stash h, small output GEMM ----
    #pragma unroll
    for (int mt = 0; mt < 2; ++mt)
        #pragma unroll
        for (int r = 0; r < 4; ++r)
            hfin[lid][w * 32 + mt * 16 + q * 4 + r] = hf[mt][r];
    __syncthreads();

    if (tid < 16 * COUT) {
        const int r  = tid / COUT;
        const int cc = tid - r * COUT;
        float acc = D_b[cc];
        #pragma unroll 8
        for (int u = 0; u < NU; ++u)
            acc = fmaf(hfin[r][u], D_w[cc * NU + u], acc);
        out[((size_t)g * 16 + r) * COUT + cc] = acc;
    }
}

extern "C" void kernel_launch(void* const* d_in, const int* in_sizes, int n_in,
                              void* d_out, int out_size, void* d_ws, size_t ws_size,
                              hipStream_t stream)
{
    const float* x   = (const float*)d_in[0];
    const float* E_w = (const float*)d_in[1];
    const float* E_b = (const float*)d_in[2];
    const float* B_p = (const float*)d_in[3];
    const float* C_p = (const float*)d_in[4];
    const float* D_w = (const float*)d_in[5];
    const float* D_b = (const float*)d_in[6];
    float* out = (float*)d_out;

    const int B  = out_size / COUT;            // 512
    const int T  = in_sizes[0] / (B * DIN);    // 1024
    const int NB = B / 16;                     // 32 blocks

    rnn_core<<<NB, 256, 0, stream>>>(x, E_w, E_b, B_p, C_p, D_w, D_b, out, T);
}